// Round 5
// baseline (157.835 us; speedup 1.0000x reference)
//
#include <hip/hip_runtime.h>

#define BB   4
#define QS   512
#define KSZ  1024
#define DD   512
#define HH   128
#define DVV  512
#define KPN  16   // k-parts in spv (64 k each)

typedef unsigned int uint;
typedef unsigned short ushort;
typedef unsigned long long ull;
typedef __attribute__((ext_vector_type(8)))  short short8;   // 8 bf16 (4 VGPRs)
typedef __attribute__((ext_vector_type(16))) float f32x16;   // MFMA 32x32 acc
typedef __attribute__((ext_vector_type(2)))  float f32x2;    // v_pk_* pair

__device__ __forceinline__ float rcp_fast(float x)  { return __builtin_amdgcn_rcpf(x); }
__device__ __forceinline__ float exp2_fast(float x) { return __builtin_amdgcn_exp2f(x); }
__device__ __forceinline__ f32x2 lo2(float4 v) { return (f32x2){v.x, v.y}; }
__device__ __forceinline__ f32x2 hi2(float4 v) { return (f32x2){v.z, v.w}; }

// split fp32 -> bf16 hi (truncate) + bf16 lo (residual); ~2^-17 rel combined
__device__ __forceinline__ void split1(float v, ushort& h, ushort& l) {
    uint u = __float_as_uint(v);
    h = (ushort)(u >> 16);
    float r = v - __uint_as_float(u & 0xffff0000u);
    l = (ushort)(__float_as_uint(r) >> 16);
}

// h-quad permutation (0,2,1,3): applied identically to eq/ek columns and wv,
// so pk-pair operands {h0,h2},{h1,h3} are register-adjacent. Sum over h is
// order-invariant -> math identical.
__device__ __forceinline__ int hperm(int h) {
    return (h & ~3) | ((h & 1) << 1) | ((h >> 1) & 1);
}

// split_kernel grid segments (q/k/W only; V^T lives in projvt_kernel)
#define NSQ  (BB * QS * DD / 4 / 256)     // 1024
#define NSK  (BB * KSZ * DD / 4 / 256)    // 2048
#define NWT  128                          // 64 per W
#define NPJ  192                          // proj blocks (768 waves)
#define NVT  (BB * (KSZ / 32) * (DVV / 32))  // 2048 V-transpose blocks

// ---------------------------------------------------------------------------
// Kernel 1: bf16 pre-split of q, k (element-wise) and W_q/W_k (transpose to
// [h][d]). Pure memory-bound, ~25 MB. Also builds the h-permuted wv copy.
// ---------------------------------------------------------------------------
__global__ __launch_bounds__(256) void split_kernel(
    const float* __restrict__ q, const float* __restrict__ k,
    const float* __restrict__ Wq, const float* __restrict__ Wk,
    const float* __restrict__ wv, float* __restrict__ wvp,
    ushort* __restrict__ qh, ushort* __restrict__ ql,
    ushort* __restrict__ kh, ushort* __restrict__ kl,
    ushort* __restrict__ wqh, ushort* __restrict__ wql,
    ushort* __restrict__ wkh, ushort* __restrict__ wkl)
{
    const int id  = blockIdx.x;
    const int tid = threadIdx.x;

    if (id < NSQ + NSK) {
        const float* src; ushort* dh; ushort* dl; size_t i;
        if (id < NSQ) { src = q; dh = qh; dl = ql; i = (size_t)id * 256 + tid; }
        else          { src = k; dh = kh; dl = kl; i = (size_t)(id - NSQ) * 256 + tid; }
        float4 v = ((const float4*)src)[i];
        ushort h0,h1,h2,h3,l0,l1,l2,l3;
        split1(v.x,h0,l0); split1(v.y,h1,l1); split1(v.z,h2,l2); split1(v.w,h3,l3);
        *(ushort4*)&dh[i * 4] = make_ushort4(h0,h1,h2,h3);
        *(ushort4*)&dl[i * 4] = make_ushort4(l0,l1,l2,l3);
        return;
    }
    // ---- W transpose + split: [512][128] -> [128][512] hi/lo ----
    __shared__ float Ts[32][33];
    int t = id - (NSQ + NSK);
    if (t == 0 && tid < HH) wvp[hperm(tid)] = wv[tid];   // permuted wv copy
    const float* W; ushort* dh; ushort* dl;
    if (t < 64) { W = Wq; dh = wqh; dl = wql; }
    else        { W = Wk; dh = wkh; dl = wkl; t -= 64; }
    const int d0 = (t >> 2) * 32, h0 = (t & 3) * 32;
    {
        const int dd = tid >> 3, c4 = (tid & 7) * 4;
        float4 v = *(const float4*)&W[(size_t)(d0 + dd) * HH + h0 + c4];
        Ts[dd][c4 + 0] = v.x; Ts[dd][c4 + 1] = v.y;
        Ts[dd][c4 + 2] = v.z; Ts[dd][c4 + 3] = v.w;
    }
    __syncthreads();
    {
        const int hh = tid >> 3, d4 = (tid & 7) * 4;
        ushort h[4], l[4];
        #pragma unroll
        for (int i = 0; i < 4; i++) split1(Ts[d4 + i][hh], h[i], l[i]);
        size_t o = (size_t)(h0 + hh) * DD + d0 + d4;
        *(ushort4*)&dh[o] = make_ushort4(h[0], h[1], h[2], h[3]);
        *(ushort4*)&dl[o] = make_ushort4(l[0], l[1], l[2], l[3]);
    }
}

// ---------------------------------------------------------------------------
// Kernel 2 (fused): blocks [0,NPJ) = projection via MFMA + exp(2x), stored
// CLAMPED at 5e4 (so spv's u=eq*ek+1 <= 2.5e9, u^4 < f32-max: the per-u
// fminf in the scores hot loop is no longer needed) and with h-quad-permuted
// columns (pk-pairing in spv). Blocks [NPJ,+NVT) = V transpose+split.
// ---------------------------------------------------------------------------
__global__ __launch_bounds__(256) void projvt_kernel(
    const ushort* __restrict__ qh, const ushort* __restrict__ ql,
    const ushort* __restrict__ kh, const ushort* __restrict__ kl,
    const ushort* __restrict__ wqh, const ushort* __restrict__ wql,
    const ushort* __restrict__ wkh, const ushort* __restrict__ wkl,
    const float* __restrict__ val,
    float* __restrict__ eq, float* __restrict__ ek,
    ushort* __restrict__ vhi, ushort* __restrict__ vlo)
{
    const int id  = blockIdx.x;
    const int tid = threadIdx.x;

    if (id >= NPJ) {
        __shared__ float Ts[32][33];
        const int t   = id - NPJ;
        const int b   = t >> 9;
        const int rem = t & 511;
        const int k0  = (rem >> 4) * 32;
        const int n0  = (rem & 15) * 32;
        {
            const int kk = tid >> 3, n4 = (tid & 7) * 4;
            float4 v = *(const float4*)&val[((size_t)b * KSZ + k0 + kk) * DVV + n0 + n4];
            Ts[kk][n4 + 0] = v.x; Ts[kk][n4 + 1] = v.y;
            Ts[kk][n4 + 2] = v.z; Ts[kk][n4 + 3] = v.w;
        }
        __syncthreads();
        {
            const int nn = tid >> 3, k4 = (tid & 7) * 4;
            ushort h[4], l[4];
            #pragma unroll
            for (int i = 0; i < 4; i++) split1(Ts[k4 + i][nn], h[i], l[i]);
            size_t o = ((size_t)b * DVV + n0 + nn) * KSZ + k0 + k4;
            *(ushort4*)&vhi[o] = make_ushort4(h[0], h[1], h[2], h[3]);
            *(ushort4*)&vlo[o] = make_ushort4(l[0], l[1], l[2], l[3]);
        }
        return;
    }

    // ---- projection: eq/ek[m][hperm] = min(exp2(C2L*sum), 5e4) ----
    const int w = tid >> 6, lane = tid & 63;
    const int row = lane & 31, kg = lane >> 5;
    const int gw = id * 4 + w;                  // 0..767

    const ushort *pa_h, *pa_l, *pb_h, *pb_l; float* op; int m0, nt;
    if (gw < 256) {
        m0 = (gw >> 2) * 32; nt = gw & 3;
        pa_h = qh; pa_l = ql; pb_h = wqh; pb_l = wql; op = eq;
    } else {
        const int g = gw - 256;
        m0 = (g >> 2) * 32; nt = g & 3;
        pa_h = kh; pa_l = kl; pb_h = wkh; pb_l = wkl; op = ek;
    }

    const ushort* ah_p = pa_h + (size_t)(m0 + row) * DD + kg * 8;
    const ushort* al_p = pa_l + (size_t)(m0 + row) * DD + kg * 8;
    const ushort* bh_p = pb_h + (size_t)(nt * 32 + row) * DD + kg * 8;
    const ushort* bl_p = pb_l + (size_t)(nt * 32 + row) * DD + kg * 8;

    f32x16 acc;
    #pragma unroll
    for (int i = 0; i < 16; i++) acc[i] = 0.f;

    #pragma unroll 8
    for (int ks = 0; ks < DD; ks += 16) {
        short8 ah = *(const short8*)(ah_p + ks);
        short8 al = *(const short8*)(al_p + ks);
        short8 bh = *(const short8*)(bh_p + ks);
        short8 bl = *(const short8*)(bl_p + ks);
        acc = __builtin_amdgcn_mfma_f32_32x32x16_bf16(ah, bh, acc, 0, 0, 0);
        acc = __builtin_amdgcn_mfma_f32_32x32x16_bf16(ah, bl, acc, 0, 0, 0);
        acc = __builtin_amdgcn_mfma_f32_32x32x16_bf16(al, bh, acc, 0, 0, 0);
    }

    const float C2L = 2.8853900817779268f;  // 2*log2(e)
    float* ob = op + (size_t)m0 * HH + nt * 32;
    const int prow = hperm(row);
    #pragma unroll
    for (int r = 0; r < 16; r++) {
        const int rb = (r & 3) + 8 * (r >> 2) + 4 * kg;
        ob[(size_t)rb * HH + prow] = fminf(exp2_fast(acc[r] * C2L), 5.0e4f);
    }
}

// ---------------------------------------------------------------------------
// Kernel 3 (fused scores+PV, R5): 1024 blocks x 256 threads, 4 blocks/CU.
// Changes vs R4 (which stalled at VALUBusy 51% from phase-lockstep clones):
//  * scores SGROUP uses v_pk_fma_f32/v_pk_mul_f32 pairs (h-quad permuted
//    inputs) and drops the 4 fminf (clamped at source): 19 -> 10 slots.
//  * MFMA(s-1) + its V^T loads are INTERLEAVED into scores(s): per group g
//    (nb=g>>1, k2=g&1) issue 2 b128 V-loads, run 4 h-iters (~400 cyc, covers
//    L2 latency), then 3 MFMAs. P is single-buffered (scores writes P only
//    at phase end, after a barrier). 16 live V-VGPRs per group in flight.
//  * tail MFMA(1) after the last P-write; ek subtile-1 reg-prefetched (T14).
// ---------------------------------------------------------------------------
__global__ __launch_bounds__(256, 4) void spv_kernel(
    const float* __restrict__ eq, const float* __restrict__ ek,
    const float* __restrict__ wvp,
    const ushort* __restrict__ vhi, const ushort* __restrict__ vlo,
    float* __restrict__ opart, float* __restrict__ rsp)
{
    __shared__ float  eqs[32][132];   // 16896 B (2-way bank alias max = free)
    __shared__ float  eks[32][132];   // 16896 B
    __shared__ ushort PhS[32][36];    //  2304 B (stride 18 words, 2-way)
    __shared__ ushort PlS[32][36];    //  2304 B   (total 38400 B -> 4 blk/CU)

    const int id  = blockIdx.x;       // 1024 = qt(16) x b(4) x kp(16)
    const int kp  = id & 15;          // id%8 = kp%8 -> (b,kp) slice XCD-local
    const int b   = (id >> 4) & 3;
    const int qt  = id >> 6;          // 0..15 (32-row q tiles)

    const int tid  = threadIdx.x;
    const int w    = tid >> 6, lane = tid & 63;
    const int tq   = tid >> 4;        // scores: q rows tq, tq+16
    const int tk   = tid & 15;        // scores: k cols tk, tk+16
    const int wn   = w * 128;         // MFMA: n range per wave
    const int arow = lane & 31;       // MFMA A row / B^T row / D col
    const int akg  = lane >> 5;       // MFMA k-group (8 k each)

    // ---- prologue: stage eq tile [32][128] + ek subtile 0 [32][128] ----
    const float* eqg = eq + ((size_t)b * QS + qt * 32) * HH;
    #pragma unroll
    for (int i = 0; i < 4; i++) {
        int f = tid + i * 256;
        *(float4*)&eqs[f >> 5][(f & 31) * 4] =
            *(const float4*)&eqg[(size_t)(f >> 5) * HH + (f & 31) * 4];
    }
    const float* ekg = ek + ((size_t)b * KSZ + kp * 64) * HH;
    #pragma unroll
    for (int i = 0; i < 4; i++) {
        int f = tid + i * 256;
        *(float4*)&eks[f >> 5][(f & 31) * 4] =
            *(const float4*)&ekg[(size_t)(f >> 5) * HH + (f & 31) * 4];
    }

    // reg-prefetch ek subtile 1 (committed to LDS after subtile-0 barrier)
    float4 eknxt[4];
    #pragma unroll
    for (int i = 0; i < 4; i++) {
        int f = tid + i * 256;
        eknxt[i] = *(const float4*)&ekg[(size_t)(32 + (f >> 5)) * HH + (f & 31) * 4];
    }
    __syncthreads();

    f32x16 acc[4];
    #pragma unroll
    for (int n = 0; n < 4; n++) {
        #pragma unroll
        for (int i = 0; i < 16; i++) acc[n][i] = 0.f;
    }
    float rowacc0 = 0.f, rowacc1 = 0.f;

    // per-lane V^T base: n-row = b*DVV + wn + arow, k base = kp*64 + akg*8
    const size_t vrow0 = ((size_t)b * DVV + wn + arow) * KSZ + kp * 64 + akg * 8;
    const ushort* vhb = vhi + vrow0;
    const ushort* vlb = vlo + vrow0;

    const f32x2 one2 = {1.0f, 1.0f};

    // packed-pair SGROUP: inputs h-quad permuted (phys = h0,h2,h1,h3), so
    // lo2 = {u_h0,u_h2}, hi2 = {u_h1,u_h3}; p = {p01,p23}; n = {n01,n23}.
#define SGROUP(eq4, ek4, sacc) { \
    f32x2 u02 = __builtin_elementwise_fma(lo2(eq4), lo2(ek4), one2); \
    f32x2 u13 = __builtin_elementwise_fma(hi2(eq4), hi2(ek4), one2); \
    f32x2 p_  = u02 * u13; \
    f32x2 n_  = __builtin_elementwise_fma(wA, u13, wB * u02); \
    float N_  = fmaf(n_.x, p_.y, n_.y * p_.x); \
    sacc = fmaf(N_, rcp_fast(p_.x * p_.y), sacc); }

#define HITER(h) { \
    float4 wp4 = *(const float4*)&wvp[h]; \
    f32x2 wA = lo2(wp4), wB = hi2(wp4); \
    float4 eqa = *(const float4*)&eqs[tq][h]; \
    float4 eqb = *(const float4*)&eqs[tq + 16][h]; \
    float4 eka = *(const float4*)&eks[tk][h]; \
    float4 ekb = *(const float4*)&eks[tk + 16][h]; \
    SGROUP(eqa, eka, s00); SGROUP(eqa, ekb, s01); \
    SGROUP(eqb, eka, s10); SGROUP(eqb, ekb, s11); }

#define VLOAD(vh_, vl_, g, sp) { \
    const size_t o_ = (size_t)((g) >> 1) * 32 * KSZ + (size_t)(sp) * 32 + ((g) & 1) * 16; \
    vh_ = *(const short8*)(vhb + o_); \
    vl_ = *(const short8*)(vlb + o_); }

#define MFMASUB(g, vh_, vl_) { \
    const int k2_ = (g) & 1, nb_ = (g) >> 1; \
    short8 ah_, al_; \
    { const ull* p = (const ull*)&PhS[arow][k2_ * 16 + akg * 8]; \
      ((ull*)&ah_)[0] = p[0]; ((ull*)&ah_)[1] = p[1]; } \
    { const ull* p = (const ull*)&PlS[arow][k2_ * 16 + akg * 8]; \
      ((ull*)&al_)[0] = p[0]; ((ull*)&al_)[1] = p[1]; } \
    acc[nb_] = __builtin_amdgcn_mfma_f32_32x32x16_bf16(ah_, vh_, acc[nb_], 0, 0, 0); \
    acc[nb_] = __builtin_amdgcn_mfma_f32_32x32x16_bf16(ah_, vl_, acc[nb_], 0, 0, 0); \
    acc[nb_] = __builtin_amdgcn_mfma_f32_32x32x16_bf16(al_, vh_, acc[nb_], 0, 0, 0); }

#define PWRITE() { \
    const float CN = -2.8853900817779268f; \
    float p00 = exp2_fast(s00 * CN), p01v = exp2_fast(s01 * CN); \
    float p10 = exp2_fast(s10 * CN), p11  = exp2_fast(s11 * CN); \
    ushort hh_, ll_; \
    split1(p00,  hh_, ll_); PhS[tq][tk]           = hh_; PlS[tq][tk]           = ll_; \
    split1(p01v, hh_, ll_); PhS[tq][tk + 16]      = hh_; PlS[tq][tk + 16]      = ll_; \
    split1(p10,  hh_, ll_); PhS[tq + 16][tk]      = hh_; PlS[tq + 16][tk]      = ll_; \
    split1(p11,  hh_, ll_); PhS[tq + 16][tk + 16] = hh_; PlS[tq + 16][tk + 16] = ll_; \
    rowacc0 += p00 + p01v; rowacc1 += p10 + p11; }

    float s00, s01, s10, s11;

    // ---------------- subtile 0: scores only ----------------
    s00 = s01 = s10 = s11 = 0.f;
    #pragma unroll 4
    for (int h = 0; h < HH; h += 4) HITER(h);
    __syncthreads();                 // all scores(0) reads of eks done
    PWRITE();                        // P(0) -> LDS
    #pragma unroll
    for (int i = 0; i < 4; i++) {    // commit ek subtile 1
        int f = tid + i * 256;
        *(float4*)&eks[f >> 5][(f & 31) * 4] = eknxt[i];
    }
    __syncthreads();                 // P(0), eks(1) visible

    // ------- subtile 1: scores(1) interleaved with MFMA(0) -------
    s00 = s01 = s10 = s11 = 0.f;
    {
        short8 vh, vl, vhn, vln;
        VLOAD(vh, vl, 0, 0);
        #pragma unroll
        for (int g = 0; g < 8; ++g) {
            #pragma unroll
            for (int hh = 0; hh < 4; ++hh) HITER(g * 16 + hh * 4);
            if (g < 7) { VLOAD(vhn, vln, g + 1, 0); }
            MFMASUB(g, vh, vl);
            if (g < 7) { vh = vhn; vl = vln; }
        }
    }
    __syncthreads();                 // MFMA(0) P-reads done
    PWRITE();                        // P(1) -> LDS
    __syncthreads();                 // P(1) visible

    // ---------------- tail: MFMA(1) ----------------
    {
        short8 vh, vl, vhn, vln;
        VLOAD(vh, vl, 0, 1);
        #pragma unroll
        for (int g = 0; g < 8; ++g) {
            if (g < 7) { VLOAD(vhn, vln, g + 1, 1); }
            MFMASUB(g, vh, vl);
            if (g < 7) { vh = vhn; vl = vln; }
        }
    }
#undef SGROUP
#undef HITER
#undef VLOAD
#undef MFMASUB
#undef PWRITE

    // ---- rowsum partials: reduce across the 16 k-threads of each q row ----
    #pragma unroll
    for (int m = 8; m; m >>= 1) {
        rowacc0 += __shfl_xor(rowacc0, m);
        rowacc1 += __shfl_xor(rowacc1, m);
    }
    if (tk == 0) {
        rsp[((size_t)b * QS + qt * 32 + tq) * KPN + kp]      = rowacc0;
        rsp[((size_t)b * QS + qt * 32 + tq + 16) * KPN + kp] = rowacc1;
    }

    // ---- partial-output store: opart[kp][b][q][n], 128B-contiguous ----
    // C/D: col = lane&31, row = (r&3) + 8*(r>>2) + 4*akg
    float* ob = opart + (((size_t)kp * BB + b) * QS + qt * 32) * DVV + wn;
    #pragma unroll
    for (int nb = 0; nb < 4; nb++) {
        #pragma unroll
        for (int r = 0; r < 16; r++) {
            const int rb = (r & 3) + 8 * (r >> 2) + 4 * akg;
            ob[(size_t)rb * DVV + nb * 32 + arow] = acc[nb][r];
        }
    }
}

// ---------------------------------------------------------------------------
// Kernel 4: out[b][q][n] = sum_kp opart / sum_kp rsp. ~72 MB, HBM-bound.
// ---------------------------------------------------------------------------
__global__ __launch_bounds__(256) void norm_kernel(
    const float* __restrict__ opart, const float* __restrict__ rsp,
    float* __restrict__ outp)
{
    const int i  = blockIdx.x * 256 + threadIdx.x;   // 262144 f4 totals
    const int n4 = (i & 127) * 4;
    const int q  = (i >> 7) & (QS - 1);
    const int b  = i >> 16;

    const float* rp = rsp + ((size_t)b * QS + q) * KPN;
    float s = 0.f;
    #pragma unroll
    for (int j = 0; j < KPN / 4; j++) {
        float4 r = *(const float4*)(rp + j * 4);
        s += r.x + r.y + r.z + r.w;
    }
    float inv = rcp_fast(s);

    float ox = 0.f, oy = 0.f, oz = 0.f, ow = 0.f;
    #pragma unroll
    for (int kp = 0; kp < KPN; kp++) {
        float4 v = *(const float4*)&opart[(((size_t)kp * BB + b) * QS + q) * DVV + n4];
        ox += v.x; oy += v.y; oz += v.z; ow += v.w;
    }
    float4 res = make_float4(ox * inv, oy * inv, oz * inv, ow * inv);
    *(float4*)&outp[((size_t)b * QS + q) * DVV + n4] = res;
}

// ---------------------------------------------------------------------------
extern "C" void kernel_launch(void* const* d_in, const int* in_sizes, int n_in,
                              void* d_out, int out_size, void* d_ws, size_t ws_size,
                              hipStream_t stream)
{
    const float* queries = (const float*)d_in[0];
    const float* keys    = (const float*)d_in[1];
    const float* values  = (const float*)d_in[2];
    const float* Wq      = (const float*)d_in[3];
    const float* Wk      = (const float*)d_in[4];
    const float* wv      = (const float*)d_in[5];
    float* out = (float*)d_out;

    // float region
    float*  eq    = (float*)d_ws;
    float*  ek    = eq  + (size_t)BB * QS * HH;
    float*  rsp   = ek  + (size_t)BB * KSZ * HH;            // [b*Q][16] partials
    float*  wvp   = rsp + (size_t)BB * QS * KPN;            // permuted wv (128 + pad)
    float*  opart = wvp + 256;                              // [16][b][Q][Dv] = 64 MB
    // ushort region
    ushort* vhi = (ushort*)(opart + (size_t)KPN * BB * QS * DVV);
    ushort* vlo = vhi + (size_t)BB * KSZ * DVV;
    ushort* qh  = vlo + (size_t)BB * KSZ * DVV;
    ushort* ql  = qh  + (size_t)BB * QS * DD;
    ushort* kh  = ql  + (size_t)BB * QS * DD;
    ushort* kl  = kh  + (size_t)BB * KSZ * DD;
    ushort* wqh = kl  + (size_t)BB * KSZ * DD;
    ushort* wql = wqh + (size_t)HH * DD;
    ushort* wkh = wql + (size_t)HH * DD;
    ushort* wkl = wkh + (size_t)HH * DD;

    split_kernel<<<dim3(NSQ + NSK + NWT), 256, 0, stream>>>(
        queries, keys, Wq, Wk, wv, wvp, qh, ql, kh, kl, wqh, wql, wkh, wkl);

    projvt_kernel<<<dim3(NPJ + NVT), 256, 0, stream>>>(
        qh, ql, kh, kl, wqh, wql, wkh, wkl, values, eq, ek, vhi, vlo);

    spv_kernel<<<dim3(1024), 256, 0, stream>>>(eq, ek, wvp, vhi, vlo, opart, rsp);

    norm_kernel<<<dim3(1024), 256, 0, stream>>>(opart, rsp, out);
}

// Round 6
// 150.828 us; speedup vs baseline: 1.0465x; 1.0465x over previous
//
#include <hip/hip_runtime.h>

#define BB   4
#define QS   512
#define KSZ  1024
#define DD   512
#define HH   128
#define DVV  512
#define KPN  16   // k-parts in spv (64 k each)

typedef unsigned int uint;
typedef unsigned short ushort;
typedef unsigned long long ull;
typedef __attribute__((ext_vector_type(8)))  short short8;   // 8 bf16 (4 VGPRs)
typedef __attribute__((ext_vector_type(16))) float f32x16;   // MFMA 32x32 acc
typedef __attribute__((ext_vector_type(2)))  float f32x2;    // v_pk_* pair

__device__ __forceinline__ float rcp_fast(float x)  { return __builtin_amdgcn_rcpf(x); }
__device__ __forceinline__ float exp2_fast(float x) { return __builtin_amdgcn_exp2f(x); }
__device__ __forceinline__ f32x2 lo2(float4 v) { return (f32x2){v.x, v.y}; }
__device__ __forceinline__ f32x2 hi2(float4 v) { return (f32x2){v.z, v.w}; }

// split fp32 -> bf16 hi (truncate) + bf16 lo (residual); ~2^-17 rel combined
__device__ __forceinline__ void split1(float v, ushort& h, ushort& l) {
    uint u = __float_as_uint(v);
    h = (ushort)(u >> 16);
    float r = v - __uint_as_float(u & 0xffff0000u);
    l = (ushort)(__float_as_uint(r) >> 16);
}

// h-quad permutation (0,2,1,3): applied identically to eq/ek columns and wv,
// so pk-pair operands {h0,h2},{h1,h3} are register-adjacent. Sum over h is
// order-invariant -> math identical.
__device__ __forceinline__ int hperm(int h) {
    return (h & ~3) | ((h & 1) << 1) | ((h >> 1) & 1);
}

// split_kernel grid segments (q/k/W only; V^T lives in projvt_kernel)
#define NSQ  (BB * QS * DD / 4 / 256)     // 1024
#define NSK  (BB * KSZ * DD / 4 / 256)    // 2048
#define NWT  128                          // 64 per W
#define NPJ  192                          // proj blocks (768 waves)
#define NVT  (BB * (KSZ / 32) * (DVV / 32))  // 2048 V-transpose blocks

// ---------------------------------------------------------------------------
// Kernel 1: bf16 pre-split of q, k (element-wise) and W_q/W_k (transpose to
// [h][d]). Pure memory-bound, ~25 MB. Also builds the h-permuted wv copy.
// ---------------------------------------------------------------------------
__global__ __launch_bounds__(256) void split_kernel(
    const float* __restrict__ q, const float* __restrict__ k,
    const float* __restrict__ Wq, const float* __restrict__ Wk,
    const float* __restrict__ wv, float* __restrict__ wvp,
    ushort* __restrict__ qh, ushort* __restrict__ ql,
    ushort* __restrict__ kh, ushort* __restrict__ kl,
    ushort* __restrict__ wqh, ushort* __restrict__ wql,
    ushort* __restrict__ wkh, ushort* __restrict__ wkl)
{
    const int id  = blockIdx.x;
    const int tid = threadIdx.x;

    if (id < NSQ + NSK) {
        const float* src; ushort* dh; ushort* dl; size_t i;
        if (id < NSQ) { src = q; dh = qh; dl = ql; i = (size_t)id * 256 + tid; }
        else          { src = k; dh = kh; dl = kl; i = (size_t)(id - NSQ) * 256 + tid; }
        float4 v = ((const float4*)src)[i];
        ushort h0,h1,h2,h3,l0,l1,l2,l3;
        split1(v.x,h0,l0); split1(v.y,h1,l1); split1(v.z,h2,l2); split1(v.w,h3,l3);
        *(ushort4*)&dh[i * 4] = make_ushort4(h0,h1,h2,h3);
        *(ushort4*)&dl[i * 4] = make_ushort4(l0,l1,l2,l3);
        return;
    }
    // ---- W transpose + split: [512][128] -> [128][512] hi/lo ----
    __shared__ float Ts[32][33];
    int t = id - (NSQ + NSK);
    if (t == 0 && tid < HH) wvp[hperm(tid)] = wv[tid];   // permuted wv copy
    const float* W; ushort* dh; ushort* dl;
    if (t < 64) { W = Wq; dh = wqh; dl = wql; }
    else        { W = Wk; dh = wkh; dl = wkl; t -= 64; }
    const int d0 = (t >> 2) * 32, h0 = (t & 3) * 32;
    {
        const int dd = tid >> 3, c4 = (tid & 7) * 4;
        float4 v = *(const float4*)&W[(size_t)(d0 + dd) * HH + h0 + c4];
        Ts[dd][c4 + 0] = v.x; Ts[dd][c4 + 1] = v.y;
        Ts[dd][c4 + 2] = v.z; Ts[dd][c4 + 3] = v.w;
    }
    __syncthreads();
    {
        const int hh = tid >> 3, d4 = (tid & 7) * 4;
        ushort h[4], l[4];
        #pragma unroll
        for (int i = 0; i < 4; i++) split1(Ts[d4 + i][hh], h[i], l[i]);
        size_t o = (size_t)(h0 + hh) * DD + d0 + d4;
        *(ushort4*)&dh[o] = make_ushort4(h[0], h[1], h[2], h[3]);
        *(ushort4*)&dl[o] = make_ushort4(l[0], l[1], l[2], l[3]);
    }
}

// ---------------------------------------------------------------------------
// Kernel 2 (fused): blocks [0,NPJ) = projection via MFMA + exp(2x), stored
// CLAMPED at 5e4 (so spv's u=eq*ek+1 <= 2.5e9, u^4 < f32-max: no per-u
// fminf needed in the scores hot loop) and with h-quad-permuted columns
// (pk-pairing in spv). Blocks [NPJ,+NVT) = V transpose+split.
// ---------------------------------------------------------------------------
__global__ __launch_bounds__(256) void projvt_kernel(
    const ushort* __restrict__ qh, const ushort* __restrict__ ql,
    const ushort* __restrict__ kh, const ushort* __restrict__ kl,
    const ushort* __restrict__ wqh, const ushort* __restrict__ wql,
    const ushort* __restrict__ wkh, const ushort* __restrict__ wkl,
    const float* __restrict__ val,
    float* __restrict__ eq, float* __restrict__ ek,
    ushort* __restrict__ vhi, ushort* __restrict__ vlo)
{
    const int id  = blockIdx.x;
    const int tid = threadIdx.x;

    if (id >= NPJ) {
        __shared__ float Ts[32][33];
        const int t   = id - NPJ;
        const int b   = t >> 9;
        const int rem = t & 511;
        const int k0  = (rem >> 4) * 32;
        const int n0  = (rem & 15) * 32;
        {
            const int kk = tid >> 3, n4 = (tid & 7) * 4;
            float4 v = *(const float4*)&val[((size_t)b * KSZ + k0 + kk) * DVV + n0 + n4];
            Ts[kk][n4 + 0] = v.x; Ts[kk][n4 + 1] = v.y;
            Ts[kk][n4 + 2] = v.z; Ts[kk][n4 + 3] = v.w;
        }
        __syncthreads();
        {
            const int nn = tid >> 3, k4 = (tid & 7) * 4;
            ushort h[4], l[4];
            #pragma unroll
            for (int i = 0; i < 4; i++) split1(Ts[k4 + i][nn], h[i], l[i]);
            size_t o = ((size_t)b * DVV + n0 + nn) * KSZ + k0 + k4;
            *(ushort4*)&vhi[o] = make_ushort4(h[0], h[1], h[2], h[3]);
            *(ushort4*)&vlo[o] = make_ushort4(l[0], l[1], l[2], l[3]);
        }
        return;
    }

    // ---- projection: eq/ek[m][hperm] = min(exp2(C2L*sum), 5e4) ----
    const int w = tid >> 6, lane = tid & 63;
    const int row = lane & 31, kg = lane >> 5;
    const int gw = id * 4 + w;                  // 0..767

    const ushort *pa_h, *pa_l, *pb_h, *pb_l; float* op; int m0, nt;
    if (gw < 256) {
        m0 = (gw >> 2) * 32; nt = gw & 3;
        pa_h = qh; pa_l = ql; pb_h = wqh; pb_l = wql; op = eq;
    } else {
        const int g = gw - 256;
        m0 = (g >> 2) * 32; nt = g & 3;
        pa_h = kh; pa_l = kl; pb_h = wkh; pb_l = wkl; op = ek;
    }

    const ushort* ah_p = pa_h + (size_t)(m0 + row) * DD + kg * 8;
    const ushort* al_p = pa_l + (size_t)(m0 + row) * DD + kg * 8;
    const ushort* bh_p = pb_h + (size_t)(nt * 32 + row) * DD + kg * 8;
    const ushort* bl_p = pb_l + (size_t)(nt * 32 + row) * DD + kg * 8;

    f32x16 acc;
    #pragma unroll
    for (int i = 0; i < 16; i++) acc[i] = 0.f;

    #pragma unroll 8
    for (int ks = 0; ks < DD; ks += 16) {
        short8 ah = *(const short8*)(ah_p + ks);
        short8 al = *(const short8*)(al_p + ks);
        short8 bh = *(const short8*)(bh_p + ks);
        short8 bl = *(const short8*)(bl_p + ks);
        acc = __builtin_amdgcn_mfma_f32_32x32x16_bf16(ah, bh, acc, 0, 0, 0);
        acc = __builtin_amdgcn_mfma_f32_32x32x16_bf16(ah, bl, acc, 0, 0, 0);
        acc = __builtin_amdgcn_mfma_f32_32x32x16_bf16(al, bh, acc, 0, 0, 0);
    }

    const float C2L = 2.8853900817779268f;  // 2*log2(e)
    float* ob = op + (size_t)m0 * HH + nt * 32;
    const int prow = hperm(row);
    #pragma unroll
    for (int r = 0; r < 16; r++) {
        const int rb = (r & 3) + 8 * (r >> 2) + 4 * kg;
        ob[(size_t)rb * HH + prow] = fminf(exp2_fast(acc[r] * C2L), 5.0e4f);
    }
}

// ---------------------------------------------------------------------------
// Kernel 3 (fused scores+PV, R6): R4's proven phase-separated schedule
// (scores -> PWRITE -> barrier -> [ek restage] -> MFMA -> barrier; no phase
// overlap = live sets never combine, fits the 128-reg budget at 4 blk/CU;
// R5's interleave spilled: FETCH 15->38 MB, WRITE 78->121 MB of scratch)
// + R5's validated VALU cuts: pk-paired SGROUP (h-quad permuted inputs) and
// no in-loop clamps (eq/ek pre-clamped at 5e4): ~13 vs 23 slot-equivs.
// ---------------------------------------------------------------------------
__global__ __launch_bounds__(256, 4) void spv_kernel(
    const float* __restrict__ eq, const float* __restrict__ ek,
    const float* __restrict__ wvp,
    const ushort* __restrict__ vhi, const ushort* __restrict__ vlo,
    float* __restrict__ opart, float* __restrict__ rsp)
{
    __shared__ float  eqs[32][132];   // 16896 B (2-way bank alias max = free)
    __shared__ float  eks[32][132];   // 16896 B
    __shared__ ushort PhS[32][36];    //  2304 B (stride 18 words, 2-way)
    __shared__ ushort PlS[32][36];    //  2304 B   (total 38400 B -> 4 blk/CU)

    const int id  = blockIdx.x;       // 1024 = qt(16) x b(4) x kp(16)
    const int kp  = id & 15;          // id%8 = kp%8 -> (b,kp) slice XCD-local
    const int b   = (id >> 4) & 3;
    const int qt  = id >> 6;          // 0..15 (32-row q tiles)

    const int tid  = threadIdx.x;
    const int w    = tid >> 6, lane = tid & 63;
    const int tq   = tid >> 4;        // scores: q rows tq, tq+16
    const int tk   = tid & 15;        // scores: k cols tk, tk+16
    const int wn   = w * 128;         // MFMA: n range per wave
    const int arow = lane & 31;       // MFMA A row / B^T row / D col
    const int akg  = lane >> 5;       // MFMA k-group (8 k each)

    // ---- prologue: stage eq tile [32][128] + ek subtile 0 [32][128] ----
    const float* eqg = eq + ((size_t)b * QS + qt * 32) * HH;
    #pragma unroll
    for (int i = 0; i < 4; i++) {
        int f = tid + i * 256;
        *(float4*)&eqs[f >> 5][(f & 31) * 4] =
            *(const float4*)&eqg[(size_t)(f >> 5) * HH + (f & 31) * 4];
    }
    const float* ekg = ek + ((size_t)b * KSZ + kp * 64) * HH;
    #pragma unroll
    for (int i = 0; i < 4; i++) {
        int f = tid + i * 256;
        *(float4*)&eks[f >> 5][(f & 31) * 4] =
            *(const float4*)&ekg[(size_t)(f >> 5) * HH + (f & 31) * 4];
    }
    __syncthreads();

    f32x16 acc[4];
    #pragma unroll
    for (int n = 0; n < 4; n++) {
        #pragma unroll
        for (int i = 0; i < 16; i++) acc[n][i] = 0.f;
    }
    float rowacc0 = 0.f, rowacc1 = 0.f;

    // per-lane V^T base: n-row = b*DVV + wn + arow, k base = kp*64 + akg*8
    const size_t vrow0 = ((size_t)b * DVV + wn + arow) * KSZ + kp * 64 + akg * 8;
    const ushort* vhb = vhi + vrow0;
    const ushort* vlb = vlo + vrow0;

    const f32x2 one2 = {1.0f, 1.0f};

    // packed-pair SGROUP: inputs h-quad permuted (phys = h0,h2,h1,h3), so
    // lo2 = {u_h0,u_h2}, hi2 = {u_h1,u_h3}; p = {p01,p23}; n = {n01,n23}.
#define SGROUP(eq4, ek4, sacc) { \
    f32x2 u02 = __builtin_elementwise_fma(lo2(eq4), lo2(ek4), one2); \
    f32x2 u13 = __builtin_elementwise_fma(hi2(eq4), hi2(ek4), one2); \
    f32x2 p_  = u02 * u13; \
    f32x2 n_  = __builtin_elementwise_fma(wA, u13, wB * u02); \
    float N_  = fmaf(n_.x, p_.y, n_.y * p_.x); \
    sacc = fmaf(N_, rcp_fast(p_.x * p_.y), sacc); }

#define HITER(h) { \
    float4 wp4 = *(const float4*)&wvp[h]; \
    f32x2 wA = lo2(wp4), wB = hi2(wp4); \
    float4 eqa = *(const float4*)&eqs[tq][h]; \
    float4 eqb = *(const float4*)&eqs[tq + 16][h]; \
    float4 eka = *(const float4*)&eks[tk][h]; \
    float4 ekb = *(const float4*)&eks[tk + 16][h]; \
    SGROUP(eqa, eka, s00); SGROUP(eqa, ekb, s01); \
    SGROUP(eqb, eka, s10); SGROUP(eqb, ekb, s11); }

    #pragma unroll
    for (int s = 0; s < 2; s++) {
        // ---- scores: 32q x 32k, thread-tile 2q x 2k ----
        float s00 = 0.f, s01 = 0.f, s10 = 0.f, s11 = 0.f;
        #pragma unroll 4
        for (int h = 0; h < HH; h += 4) HITER(h);
        {
            const float CN = -2.8853900817779268f;  // -2*log2(e)
            float p00 = exp2_fast(s00 * CN);
            float p01v = exp2_fast(s01 * CN);
            float p10 = exp2_fast(s10 * CN);
            float p11 = exp2_fast(s11 * CN);
            ushort hh, ll;
            split1(p00,  hh, ll); PhS[tq][tk]           = hh; PlS[tq][tk]           = ll;
            split1(p01v, hh, ll); PhS[tq][tk + 16]      = hh; PlS[tq][tk + 16]      = ll;
            split1(p10,  hh, ll); PhS[tq + 16][tk]      = hh; PlS[tq + 16][tk]      = ll;
            split1(p11,  hh, ll); PhS[tq + 16][tk + 16] = hh; PlS[tq + 16][tk + 16] = ll;
            rowacc0 += p00 + p01v;
            rowacc1 += p10 + p11;
        }
        __syncthreads();   // P ready; eks consumed

        // -- during MFMA of s=0: stage ek subtile 1 (overlaps MFMA issue) --
        if (s == 0) {
            #pragma unroll
            for (int i = 0; i < 4; i++) {
                int f = tid + i * 256;
                *(float4*)&eks[f >> 5][(f & 31) * 4] =
                    *(const float4*)&ekg[(size_t)(32 + (f >> 5)) * HH + (f & 31) * 4];
            }
        }

        // ---- MFMA: P(32x32) @ V^T -> 4 n-tiles of 32 per wave ----
        short8 ah0, al0, ah1, al1;
        { const ull* p = (const ull*)&PhS[arow][akg * 8];
          ((ull*)&ah0)[0] = p[0]; ((ull*)&ah0)[1] = p[1]; }
        { const ull* p = (const ull*)&PlS[arow][akg * 8];
          ((ull*)&al0)[0] = p[0]; ((ull*)&al0)[1] = p[1]; }
        { const ull* p = (const ull*)&PhS[arow][16 + akg * 8];
          ((ull*)&ah1)[0] = p[0]; ((ull*)&ah1)[1] = p[1]; }
        { const ull* p = (const ull*)&PlS[arow][16 + akg * 8];
          ((ull*)&al1)[0] = p[0]; ((ull*)&al1)[1] = p[1]; }
        #pragma unroll
        for (int nb = 0; nb < 4; nb++) {
            const size_t o = (size_t)nb * 32 * KSZ + (size_t)s * 32;
            short8 vh0 = *(const short8*)(vhb + o);
            short8 vl0 = *(const short8*)(vlb + o);
            short8 vh1 = *(const short8*)(vhb + o + 16);
            short8 vl1 = *(const short8*)(vlb + o + 16);
            acc[nb] = __builtin_amdgcn_mfma_f32_32x32x16_bf16(ah0, vh0, acc[nb], 0, 0, 0);
            acc[nb] = __builtin_amdgcn_mfma_f32_32x32x16_bf16(ah0, vl0, acc[nb], 0, 0, 0);
            acc[nb] = __builtin_amdgcn_mfma_f32_32x32x16_bf16(al0, vh0, acc[nb], 0, 0, 0);
            acc[nb] = __builtin_amdgcn_mfma_f32_32x32x16_bf16(ah1, vh1, acc[nb], 0, 0, 0);
            acc[nb] = __builtin_amdgcn_mfma_f32_32x32x16_bf16(ah1, vl1, acc[nb], 0, 0, 0);
            acc[nb] = __builtin_amdgcn_mfma_f32_32x32x16_bf16(al1, vh1, acc[nb], 0, 0, 0);
        }
        __syncthreads();   // PhS/eks free before next scores
    }
#undef SGROUP
#undef HITER

    // ---- rowsum partials: reduce across the 16 k-threads of each q row ----
    #pragma unroll
    for (int m = 8; m; m >>= 1) {
        rowacc0 += __shfl_xor(rowacc0, m);
        rowacc1 += __shfl_xor(rowacc1, m);
    }
    if (tk == 0) {
        rsp[((size_t)b * QS + qt * 32 + tq) * KPN + kp]      = rowacc0;
        rsp[((size_t)b * QS + qt * 32 + tq + 16) * KPN + kp] = rowacc1;
    }

    // ---- partial-output store: opart[kp][b][q][n], 128B-contiguous ----
    // C/D: col = lane&31, row = (r&3) + 8*(r>>2) + 4*akg
    float* ob = opart + (((size_t)kp * BB + b) * QS + qt * 32) * DVV + wn;
    #pragma unroll
    for (int nb = 0; nb < 4; nb++) {
        #pragma unroll
        for (int r = 0; r < 16; r++) {
            const int rb = (r & 3) + 8 * (r >> 2) + 4 * akg;
            ob[(size_t)rb * DVV + nb * 32 + arow] = acc[nb][r];
        }
    }
}

// ---------------------------------------------------------------------------
// Kernel 4: out[b][q][n] = sum_kp opart / sum_kp rsp. ~72 MB, HBM-bound.
// ---------------------------------------------------------------------------
__global__ __launch_bounds__(256) void norm_kernel(
    const float* __restrict__ opart, const float* __restrict__ rsp,
    float* __restrict__ outp)
{
    const int i  = blockIdx.x * 256 + threadIdx.x;   // 262144 f4 totals
    const int n4 = (i & 127) * 4;
    const int q  = (i >> 7) & (QS - 1);
    const int b  = i >> 16;

    const float* rp = rsp + ((size_t)b * QS + q) * KPN;
    float s = 0.f;
    #pragma unroll
    for (int j = 0; j < KPN / 4; j++) {
        float4 r = *(const float4*)(rp + j * 4);
        s += r.x + r.y + r.z + r.w;
    }
    float inv = rcp_fast(s);

    float ox = 0.f, oy = 0.f, oz = 0.f, ow = 0.f;
    #pragma unroll
    for (int kp = 0; kp < KPN; kp++) {
        float4 v = *(const float4*)&opart[(((size_t)kp * BB + b) * QS + q) * DVV + n4];
        ox += v.x; oy += v.y; oz += v.z; ow += v.w;
    }
    float4 res = make_float4(ox * inv, oy * inv, oz * inv, ow * inv);
    *(float4*)&outp[((size_t)b * QS + q) * DVV + n4] = res;
}

// ---------------------------------------------------------------------------
extern "C" void kernel_launch(void* const* d_in, const int* in_sizes, int n_in,
                              void* d_out, int out_size, void* d_ws, size_t ws_size,
                              hipStream_t stream)
{
    const float* queries = (const float*)d_in[0];
    const float* keys    = (const float*)d_in[1];
    const float* values  = (const float*)d_in[2];
    const float* Wq      = (const float*)d_in[3];
    const float* Wk      = (const float*)d_in[4];
    const float* wv      = (const float*)d_in[5];
    float* out = (float*)d_out;

    // float region
    float*  eq    = (float*)d_ws;
    float*  ek    = eq  + (size_t)BB * QS * HH;
    float*  rsp   = ek  + (size_t)BB * KSZ * HH;            // [b*Q][16] partials
    float*  wvp   = rsp + (size_t)BB * QS * KPN;            // permuted wv (128 + pad)
    float*  opart = wvp + 256;                              // [16][b][Q][Dv] = 64 MB
    // ushort region
    ushort* vhi = (ushort*)(opart + (size_t)KPN * BB * QS * DVV);
    ushort* vlo = vhi + (size_t)BB * KSZ * DVV;
    ushort* qh  = vlo + (size_t)BB * KSZ * DVV;
    ushort* ql  = qh  + (size_t)BB * QS * DD;
    ushort* kh  = ql  + (size_t)BB * QS * DD;
    ushort* kl  = kh  + (size_t)BB * KSZ * DD;
    ushort* wqh = kl  + (size_t)BB * KSZ * DD;
    ushort* wql = wqh + (size_t)HH * DD;
    ushort* wkh = wql + (size_t)HH * DD;
    ushort* wkl = wkh + (size_t)HH * DD;

    split_kernel<<<dim3(NSQ + NSK + NWT), 256, 0, stream>>>(
        queries, keys, Wq, Wk, wv, wvp, qh, ql, kh, kl, wqh, wql, wkh, wkl);

    projvt_kernel<<<dim3(NPJ + NVT), 256, 0, stream>>>(
        qh, ql, kh, kl, wqh, wql, wkh, wkl, values, eq, ek, vhi, vlo);

    spv_kernel<<<dim3(1024), 256, 0, stream>>>(eq, ek, wvp, vhi, vlo, opart, rsp);

    norm_kernel<<<dim3(1024), 256, 0, stream>>>(opart, rsp, out);
}

// Round 7
// 147.443 us; speedup vs baseline: 1.0705x; 1.0230x over previous
//
#include <hip/hip_runtime.h>

#define BB   4
#define QS   512
#define KSZ  1024
#define DD   512
#define HH   128
#define DVV  512
#define KPN  16   // k-parts in spv (64 k each)

typedef unsigned int uint;
typedef unsigned short ushort;
typedef unsigned long long ull;
typedef __attribute__((ext_vector_type(8)))  short short8;   // 8 bf16 (4 VGPRs)
typedef __attribute__((ext_vector_type(16))) float f32x16;   // MFMA 32x32 acc
typedef __attribute__((ext_vector_type(2)))  float f32x2;    // v_pk_* pair

__device__ __forceinline__ float rcp_fast(float x)  { return __builtin_amdgcn_rcpf(x); }
__device__ __forceinline__ float exp2_fast(float x) { return __builtin_amdgcn_exp2f(x); }
__device__ __forceinline__ f32x2 lo2(float4 v) { return (f32x2){v.x, v.y}; }
__device__ __forceinline__ f32x2 hi2(float4 v) { return (f32x2){v.z, v.w}; }

// split fp32 -> bf16 hi (truncate) + bf16 lo (residual); ~2^-17 rel combined
__device__ __forceinline__ void split1(float v, ushort& h, ushort& l) {
    uint u = __float_as_uint(v);
    h = (ushort)(u >> 16);
    float r = v - __uint_as_float(u & 0xffff0000u);
    l = (ushort)(__float_as_uint(r) >> 16);
}

// h-quad permutation (0,2,1,3): applied identically to eq/ek columns and wv,
// so pk-pair operands {h0,h2},{h1,h3} are register-adjacent. Sum over h is
// order-invariant -> math identical.
__device__ __forceinline__ int hperm(int h) {
    return (h & ~3) | ((h & 1) << 1) | ((h >> 1) & 1);
}

// split_kernel grid segments (q/k/W only; V^T lives in projvt_kernel)
#define NSQ  (BB * QS * DD / 4 / 256)     // 1024
#define NSK  (BB * KSZ * DD / 4 / 256)    // 2048
#define NWT  128                          // 64 per W
#define NPJ  192                          // proj blocks (768 waves)
#define NVT  (BB * (KSZ / 32) * (DVV / 32))  // 2048 V-transpose blocks

// ---------------------------------------------------------------------------
// Kernel 1: bf16 pre-split of q, k (element-wise) and W_q/W_k (transpose to
// [h][d]). Pure memory-bound, ~25 MB. Also builds the h-permuted wv copy.
// ---------------------------------------------------------------------------
__global__ __launch_bounds__(256) void split_kernel(
    const float* __restrict__ q, const float* __restrict__ k,
    const float* __restrict__ Wq, const float* __restrict__ Wk,
    const float* __restrict__ wv, float* __restrict__ wvp,
    ushort* __restrict__ qh, ushort* __restrict__ ql,
    ushort* __restrict__ kh, ushort* __restrict__ kl,
    ushort* __restrict__ wqh, ushort* __restrict__ wql,
    ushort* __restrict__ wkh, ushort* __restrict__ wkl)
{
    const int id  = blockIdx.x;
    const int tid = threadIdx.x;

    if (id < NSQ + NSK) {
        const float* src; ushort* dh; ushort* dl; size_t i;
        if (id < NSQ) { src = q; dh = qh; dl = ql; i = (size_t)id * 256 + tid; }
        else          { src = k; dh = kh; dl = kl; i = (size_t)(id - NSQ) * 256 + tid; }
        float4 v = ((const float4*)src)[i];
        ushort h0,h1,h2,h3,l0,l1,l2,l3;
        split1(v.x,h0,l0); split1(v.y,h1,l1); split1(v.z,h2,l2); split1(v.w,h3,l3);
        *(ushort4*)&dh[i * 4] = make_ushort4(h0,h1,h2,h3);
        *(ushort4*)&dl[i * 4] = make_ushort4(l0,l1,l2,l3);
        return;
    }
    // ---- W transpose + split: [512][128] -> [128][512] hi/lo ----
    __shared__ float Ts[32][33];
    int t = id - (NSQ + NSK);
    if (t == 0 && tid < HH) wvp[hperm(tid)] = wv[tid];   // permuted wv copy
    const float* W; ushort* dh; ushort* dl;
    if (t < 64) { W = Wq; dh = wqh; dl = wql; }
    else        { W = Wk; dh = wkh; dl = wkl; t -= 64; }
    const int d0 = (t >> 2) * 32, h0 = (t & 3) * 32;
    {
        const int dd = tid >> 3, c4 = (tid & 7) * 4;
        float4 v = *(const float4*)&W[(size_t)(d0 + dd) * HH + h0 + c4];
        Ts[dd][c4 + 0] = v.x; Ts[dd][c4 + 1] = v.y;
        Ts[dd][c4 + 2] = v.z; Ts[dd][c4 + 3] = v.w;
    }
    __syncthreads();
    {
        const int hh = tid >> 3, d4 = (tid & 7) * 4;
        ushort h[4], l[4];
        #pragma unroll
        for (int i = 0; i < 4; i++) split1(Ts[d4 + i][hh], h[i], l[i]);
        size_t o = (size_t)(h0 + hh) * DD + d0 + d4;
        *(ushort4*)&dh[o] = make_ushort4(h[0], h[1], h[2], h[3]);
        *(ushort4*)&dl[o] = make_ushort4(l[0], l[1], l[2], l[3]);
    }
}

// ---------------------------------------------------------------------------
// Kernel 2 (fused): blocks [0,NPJ) = projection via MFMA + exp(2x), stored
// CLAMPED at 5e4 (so spv's u=eq*ek+1 <= 2.5e9, u^4 < f32-max: no per-u
// fminf needed in the scores hot loop) and with h-quad-permuted columns
// (pk-pairing in spv). Blocks [NPJ,+NVT) = V transpose+split.
// ---------------------------------------------------------------------------
__global__ __launch_bounds__(256) void projvt_kernel(
    const ushort* __restrict__ qh, const ushort* __restrict__ ql,
    const ushort* __restrict__ kh, const ushort* __restrict__ kl,
    const ushort* __restrict__ wqh, const ushort* __restrict__ wql,
    const ushort* __restrict__ wkh, const ushort* __restrict__ wkl,
    const float* __restrict__ val,
    float* __restrict__ eq, float* __restrict__ ek,
    ushort* __restrict__ vhi, ushort* __restrict__ vlo)
{
    const int id  = blockIdx.x;
    const int tid = threadIdx.x;

    if (id >= NPJ) {
        __shared__ float Ts[32][33];
        const int t   = id - NPJ;
        const int b   = t >> 9;
        const int rem = t & 511;
        const int k0  = (rem >> 4) * 32;
        const int n0  = (rem & 15) * 32;
        {
            const int kk = tid >> 3, n4 = (tid & 7) * 4;
            float4 v = *(const float4*)&val[((size_t)b * KSZ + k0 + kk) * DVV + n0 + n4];
            Ts[kk][n4 + 0] = v.x; Ts[kk][n4 + 1] = v.y;
            Ts[kk][n4 + 2] = v.z; Ts[kk][n4 + 3] = v.w;
        }
        __syncthreads();
        {
            const int nn = tid >> 3, k4 = (tid & 7) * 4;
            ushort h[4], l[4];
            #pragma unroll
            for (int i = 0; i < 4; i++) split1(Ts[k4 + i][nn], h[i], l[i]);
            size_t o = ((size_t)b * DVV + n0 + nn) * KSZ + k0 + k4;
            *(ushort4*)&vhi[o] = make_ushort4(h[0], h[1], h[2], h[3]);
            *(ushort4*)&vlo[o] = make_ushort4(l[0], l[1], l[2], l[3]);
        }
        return;
    }

    // ---- projection: eq/ek[m][hperm] = min(exp2(C2L*sum), 5e4) ----
    const int w = tid >> 6, lane = tid & 63;
    const int row = lane & 31, kg = lane >> 5;
    const int gw = id * 4 + w;                  // 0..767

    const ushort *pa_h, *pa_l, *pb_h, *pb_l; float* op; int m0, nt;
    if (gw < 256) {
        m0 = (gw >> 2) * 32; nt = gw & 3;
        pa_h = qh; pa_l = ql; pb_h = wqh; pb_l = wql; op = eq;
    } else {
        const int g = gw - 256;
        m0 = (g >> 2) * 32; nt = g & 3;
        pa_h = kh; pa_l = kl; pb_h = wkh; pb_l = wkl; op = ek;
    }

    const ushort* ah_p = pa_h + (size_t)(m0 + row) * DD + kg * 8;
    const ushort* al_p = pa_l + (size_t)(m0 + row) * DD + kg * 8;
    const ushort* bh_p = pb_h + (size_t)(nt * 32 + row) * DD + kg * 8;
    const ushort* bl_p = pb_l + (size_t)(nt * 32 + row) * DD + kg * 8;

    f32x16 acc;
    #pragma unroll
    for (int i = 0; i < 16; i++) acc[i] = 0.f;

    #pragma unroll 8
    for (int ks = 0; ks < DD; ks += 16) {
        short8 ah = *(const short8*)(ah_p + ks);
        short8 al = *(const short8*)(al_p + ks);
        short8 bh = *(const short8*)(bh_p + ks);
        short8 bl = *(const short8*)(bl_p + ks);
        acc = __builtin_amdgcn_mfma_f32_32x32x16_bf16(ah, bh, acc, 0, 0, 0);
        acc = __builtin_amdgcn_mfma_f32_32x32x16_bf16(ah, bl, acc, 0, 0, 0);
        acc = __builtin_amdgcn_mfma_f32_32x32x16_bf16(al, bh, acc, 0, 0, 0);
    }

    const float C2L = 2.8853900817779268f;  // 2*log2(e)
    float* ob = op + (size_t)m0 * HH + nt * 32;
    const int prow = hperm(row);
    #pragma unroll
    for (int r = 0; r < 16; r++) {
        const int rb = (r & 3) + 8 * (r >> 2) + 4 * kg;
        ob[(size_t)rb * HH + prow] = fminf(exp2_fast(acc[r] * C2L), 5.0e4f);
    }
}

// ---------------------------------------------------------------------------
// Kernel 3 (fused scores+PV, R7): 512 blocks x 256 threads, 2 blocks/CU.
// Tile: q=64, k-part=64 (KPN=16), ONE scores phase (no subtile loop).
// Scores thread-tile 4q x 4k: 8 ds_read_b128 per 16 SGROUPs = 0.5/SGROUP
// (R6's 2x2 = 1.0/SGROUP was LDS-issue-bound: per-CU LDS 768 cyc vs VALU
// ~600 -> VALUBusy 45%). LDS: eqs+eks = 67.6 KB; P[64][68] hi/lo (17.4 KB)
// OVERLAYS the dead eks region after the post-scores barrier -> 2 blocks/CU.
// launch_bounds(256,2) -> 256-reg budget: acc (2x4 f32x16 = 128) init'd
// AFTER scores so phase live-sets never combine (R5's spill lesson).
// MFMA: 2 q-halves x 4 nb x 4 kb x 3, proven 32x32x16 layouts; V^T from L2
// (XCD-local via id%8 = kp%8). 3 barriers total.
// ---------------------------------------------------------------------------
__global__ __launch_bounds__(256, 2) void spv_kernel(
    const float* __restrict__ eq, const float* __restrict__ ek,
    const float* __restrict__ wvp,
    const ushort* __restrict__ vhi, const ushort* __restrict__ vlo,
    float* __restrict__ opart, float* __restrict__ rsp)
{
    __shared__ float eqs[64][132];    // 33792 B
    __shared__ float eks[64][132];    // 33792 B (scores); P overlay (MFMA)
    // P overlay: PhS[64][68] + PlS[64][68] ushort = 17408 B <= 33792
    ushort (*PhS)[68] = (ushort (*)[68])&eks[0][0];
    ushort (*PlS)[68] = (ushort (*)[68])((ushort*)&eks[0][0] + 64 * 68);

    const int id  = blockIdx.x;       // 512 = qt(8) x b(4) x kp(16)
    const int kp  = ((id >> 3) & 1) * 8 + (id & 7);  // id%8 = kp%8 -> XCD-local
    const int b   = (id >> 4) & 3;
    const int qt  = id >> 6;          // 0..7 (64-row q tiles)

    const int tid  = threadIdx.x;
    const int w    = tid >> 6, lane = tid & 63;
    const int tq   = tid >> 4;        // scores: q rows tq + 16a
    const int tk   = tid & 15;        // scores: k cols tk + 16c
    const int wn   = w * 128;         // MFMA: n range per wave
    const int arow = lane & 31;       // MFMA A row / D col
    const int akg  = lane >> 5;       // MFMA k-group (8 k each)

    // ---- prologue: stage eq tile [64][128] + ek tile [64][128] ----
    const float* eqg = eq + ((size_t)b * QS + qt * 64) * HH;
    const float* ekg = ek + ((size_t)b * KSZ + kp * 64) * HH;
    #pragma unroll
    for (int i = 0; i < 8; i++) {
        int f = tid + i * 256;
        *(float4*)&eqs[f >> 5][(f & 31) * 4] =
            *(const float4*)&eqg[(size_t)(f >> 5) * HH + (f & 31) * 4];
    }
    #pragma unroll
    for (int i = 0; i < 8; i++) {
        int f = tid + i * 256;
        *(float4*)&eks[f >> 5][(f & 31) * 4] =
            *(const float4*)&ekg[(size_t)(f >> 5) * HH + (f & 31) * 4];
    }
    __syncthreads();

    const f32x2 one2 = {1.0f, 1.0f};

    // packed-pair SGROUP: inputs h-quad permuted (phys = h0,h2,h1,h3), so
    // lo2 = {u_h0,u_h2}, hi2 = {u_h1,u_h3}; p = {p01,p23}; n = {n01,n23}.
#define SGROUP(eq4, ek4, sacc) { \
    f32x2 u02 = __builtin_elementwise_fma(lo2(eq4), lo2(ek4), one2); \
    f32x2 u13 = __builtin_elementwise_fma(hi2(eq4), hi2(ek4), one2); \
    f32x2 p_  = u02 * u13; \
    f32x2 n_  = __builtin_elementwise_fma(wA, u13, wB * u02); \
    float N_  = fmaf(n_.x, p_.y, n_.y * p_.x); \
    sacc = fmaf(N_, rcp_fast(p_.x * p_.y), sacc); }

    // ---- scores: 64q x 64k, thread-tile 4q x 4k ----
    float s[4][4];
    #pragma unroll
    for (int a = 0; a < 4; a++)
        #pragma unroll
        for (int c = 0; c < 4; c++) s[a][c] = 0.f;

    #pragma unroll 4
    for (int h = 0; h < HH; h += 4) {
        float4 wp4 = *(const float4*)&wvp[h];      // uniform -> s_load
        f32x2 wA = lo2(wp4), wB = hi2(wp4);
        float4 eq4[4], ek4[4];
        #pragma unroll
        for (int a = 0; a < 4; a++) eq4[a] = *(const float4*)&eqs[tq + 16 * a][h];
        #pragma unroll
        for (int c = 0; c < 4; c++) ek4[c] = *(const float4*)&eks[tk + 16 * c][h];
        #pragma unroll
        for (int a = 0; a < 4; a++) {
            #pragma unroll
            for (int c = 0; c < 4; c++) SGROUP(eq4[a], ek4[c], s[a][c]);
        }
    }
#undef SGROUP

    // exp2 + split + rowsum BEFORE the barrier (hides under barrier wait)
    const float CN = -2.8853900817779268f;  // -2*log2(e)
    float pv[4][4];
    ushort phv[4][4], plv[4][4];
    float rowacc[4] = {0.f, 0.f, 0.f, 0.f};
    #pragma unroll
    for (int a = 0; a < 4; a++) {
        #pragma unroll
        for (int c = 0; c < 4; c++) {
            pv[a][c] = exp2_fast(s[a][c] * CN);
            split1(pv[a][c], phv[a][c], plv[a][c]);
            rowacc[a] += pv[a][c];
        }
    }

    __syncthreads();   // all eks reads done -> overlay region free

    // ---- P -> LDS overlay ----
    #pragma unroll
    for (int a = 0; a < 4; a++) {
        #pragma unroll
        for (int c = 0; c < 4; c++) {
            PhS[tq + 16 * a][tk + 16 * c] = phv[a][c];
            PlS[tq + 16 * a][tk + 16 * c] = plv[a][c];
        }
    }

    // ---- rowsum partials: reduce across the 16 k-threads of each q row ----
    #pragma unroll
    for (int m = 8; m; m >>= 1) {
        #pragma unroll
        for (int a = 0; a < 4; a++) rowacc[a] += __shfl_xor(rowacc[a], m);
    }
    if (tk == 0) {
        #pragma unroll
        for (int a = 0; a < 4; a++)
            rsp[((size_t)b * QS + qt * 64 + tq + 16 * a) * KPN + kp] = rowacc[a];
    }

    __syncthreads();   // P visible to all waves

    // ---- MFMA: P(64x64) @ V^T -> per wave: 2 q-halves x 4 n-tiles of 32 ----
    f32x16 acc[2][4];
    #pragma unroll
    for (int hlf = 0; hlf < 2; hlf++)
        #pragma unroll
        for (int nb = 0; nb < 4; nb++)
            #pragma unroll
            for (int i = 0; i < 16; i++) acc[hlf][nb][i] = 0.f;

    // per-lane V^T base: n-row = b*DVV + wn + arow, k base = kp*64 + akg*8
    const size_t vrow0 = ((size_t)b * DVV + wn + arow) * KSZ + kp * 64 + akg * 8;
    const ushort* vhb = vhi + vrow0;
    const ushort* vlb = vlo + vrow0;

    #pragma unroll
    for (int kb = 0; kb < 4; kb++) {            // k-blocks of 16
        short8 ah[2], al[2];
        #pragma unroll
        for (int hlf = 0; hlf < 2; hlf++) {
            { const ull* p = (const ull*)&PhS[hlf * 32 + arow][kb * 16 + akg * 8];
              ((ull*)&ah[hlf])[0] = p[0]; ((ull*)&ah[hlf])[1] = p[1]; }
            { const ull* p = (const ull*)&PlS[hlf * 32 + arow][kb * 16 + akg * 8];
              ((ull*)&al[hlf])[0] = p[0]; ((ull*)&al[hlf])[1] = p[1]; }
        }
        #pragma unroll
        for (int nb = 0; nb < 4; nb++) {
            const size_t o = (size_t)nb * 32 * KSZ + kb * 16;
            short8 vh = *(const short8*)(vhb + o);
            short8 vl = *(const short8*)(vlb + o);
            #pragma unroll
            for (int hlf = 0; hlf < 2; hlf++) {
                acc[hlf][nb] = __builtin_amdgcn_mfma_f32_32x32x16_bf16(ah[hlf], vh, acc[hlf][nb], 0, 0, 0);
                acc[hlf][nb] = __builtin_amdgcn_mfma_f32_32x32x16_bf16(ah[hlf], vl, acc[hlf][nb], 0, 0, 0);
                acc[hlf][nb] = __builtin_amdgcn_mfma_f32_32x32x16_bf16(al[hlf], vh, acc[hlf][nb], 0, 0, 0);
            }
        }
    }

    // ---- partial-output store: opart[kp][b][q][n], 128B-contiguous ----
    // C/D: col = lane&31, row = (r&3) + 8*(r>>2) + 4*akg
    #pragma unroll
    for (int hlf = 0; hlf < 2; hlf++) {
        float* ob = opart + (((size_t)kp * BB + b) * QS + qt * 64 + hlf * 32) * DVV + wn;
        #pragma unroll
        for (int nb = 0; nb < 4; nb++) {
            #pragma unroll
            for (int r = 0; r < 16; r++) {
                const int rb = (r & 3) + 8 * (r >> 2) + 4 * akg;
                ob[(size_t)rb * DVV + nb * 32 + arow] = acc[hlf][nb][r];
            }
        }
    }
}

// ---------------------------------------------------------------------------
// Kernel 4: out[b][q][n] = sum_kp opart / sum_kp rsp. ~72 MB, HBM-bound.
// ---------------------------------------------------------------------------
__global__ __launch_bounds__(256) void norm_kernel(
    const float* __restrict__ opart, const float* __restrict__ rsp,
    float* __restrict__ outp)
{
    const int i  = blockIdx.x * 256 + threadIdx.x;   // 262144 f4 totals
    const int n4 = (i & 127) * 4;
    const int q  = (i >> 7) & (QS - 1);
    const int b  = i >> 16;

    const float* rp = rsp + ((size_t)b * QS + q) * KPN;
    float s = 0.f;
    #pragma unroll
    for (int j = 0; j < KPN / 4; j++) {
        float4 r = *(const float4*)(rp + j * 4);
        s += r.x + r.y + r.z + r.w;
    }
    float inv = rcp_fast(s);

    float ox = 0.f, oy = 0.f, oz = 0.f, ow = 0.f;
    #pragma unroll
    for (int kp = 0; kp < KPN; kp++) {
        float4 v = *(const float4*)&opart[(((size_t)kp * BB + b) * QS + q) * DVV + n4];
        ox += v.x; oy += v.y; oz += v.z; ow += v.w;
    }
    float4 res = make_float4(ox * inv, oy * inv, oz * inv, ow * inv);
    *(float4*)&outp[((size_t)b * QS + q) * DVV + n4] = res;
}

// ---------------------------------------------------------------------------
extern "C" void kernel_launch(void* const* d_in, const int* in_sizes, int n_in,
                              void* d_out, int out_size, void* d_ws, size_t ws_size,
                              hipStream_t stream)
{
    const float* queries = (const float*)d_in[0];
    const float* keys    = (const float*)d_in[1];
    const float* values  = (const float*)d_in[2];
    const float* Wq      = (const float*)d_in[3];
    const float* Wk      = (const float*)d_in[4];
    const float* wv      = (const float*)d_in[5];
    float* out = (float*)d_out;

    // float region
    float*  eq    = (float*)d_ws;
    float*  ek    = eq  + (size_t)BB * QS * HH;
    float*  rsp   = ek  + (size_t)BB * KSZ * HH;            // [b*Q][16] partials
    float*  wvp   = rsp + (size_t)BB * QS * KPN;            // permuted wv (128 + pad)
    float*  opart = wvp + 256;                              // [16][b][Q][Dv] = 64 MB
    // ushort region
    ushort* vhi = (ushort*)(opart + (size_t)KPN * BB * QS * DVV);
    ushort* vlo = vhi + (size_t)BB * KSZ * DVV;
    ushort* qh  = vlo + (size_t)BB * KSZ * DVV;
    ushort* ql  = qh  + (size_t)BB * QS * DD;
    ushort* kh  = ql  + (size_t)BB * QS * DD;
    ushort* kl  = kh  + (size_t)BB * KSZ * DD;
    ushort* wqh = kl  + (size_t)BB * KSZ * DD;
    ushort* wql = wqh + (size_t)HH * DD;
    ushort* wkh = wql + (size_t)HH * DD;
    ushort* wkl = wkh + (size_t)HH * DD;

    split_kernel<<<dim3(NSQ + NSK + NWT), 256, 0, stream>>>(
        queries, keys, Wq, Wk, wv, wvp, qh, ql, kh, kl, wqh, wql, wkh, wkl);

    projvt_kernel<<<dim3(NPJ + NVT), 256, 0, stream>>>(
        qh, ql, kh, kl, wqh, wql, wkh, wkl, values, eq, ek, vhi, vlo);

    spv_kernel<<<dim3(512), 256, 0, stream>>>(eq, ek, wvp, vhi, vlo, opart, rsp);

    norm_kernel<<<dim3(1024), 256, 0, stream>>>(opart, rsp, out);
}